// Round 7
// baseline (214.310 us; speedup 1.0000x reference)
//
#include <hip/hip_runtime.h>
#include <stdint.h>

// LinearAttention on MI355X — round 11: barrier-free k1/k3.
//  - k1r: W-tile resident in LDS (one prologue barrier, read-only after);
//    X operand loaded DIRECTLY global->registers (MFMA B-frag = 16B/lane).
//    Zero barriers in the main loop; ILP + 8 free waves/CU hide latency.
//  - k3r: both expK and V fragments register-direct from kv; no LDS, no
//    barriers; 16 n-slices (512 blocks, 2/CU); atomicAdd ctx epilogue.
//  - k4/k5/k6 keep the round-10 dbuf mfma_bt (passed, small kernels).
//
// final_b = N_b · x_b + bias;  N_b = (W_out ⊙ ctx_b) · W_q;
// ctx_b[h] = (1/rowsum) · exp(K)·V^T  (exp w/o max-subtraction: K~N(0,0.64), safe).
//
// ws layout (bytes):
//   xbT    bf16 [8][4096][256]  @ 0          (16,777,216)
//   wkvb   bf16 [1024][256]     @ 16777216   (   524,288)
//   woutb  bf16 [256][512]      @ 17301504   (   262,144)
//   wqT    bf16 [256][512]      @ 17563648   (   262,144)
//   ctx    f32  [32][128][128]  @ 17825792   ( 2,097,152)  atomic accum
//   rowsum f32  [8][512]        @ 19922944   (    16,384)  atomic accum
//   ctxb   bf16 [32][128][128]  @ 19939328   ( 1,048,576)
//   Mb     bf16 [8][256][512]   @ 20987904   ( 2,097,152)
//   Nb     bf16 [8][256][256]   @ 23085056   ( 1,048,576)
//   kv     bf16 [8][1024][4096] @ 24133632   (67,108,864)  K part = exp(K)
// total 91,242,496 B

using frag8 = __attribute__((ext_vector_type(8))) short;   // 8 x bf16
using f32x4 = __attribute__((ext_vector_type(4))) float;

__device__ __forceinline__ unsigned short f2bf(float f) {
    union { float f; unsigned int u; } c; c.f = f;
    unsigned int u = c.u;
    return (unsigned short)((u + 0x7FFFu + ((u >> 16) & 1u)) >> 16);
}

__device__ __forceinline__ void gl_lds16(const void* g, void* l) {
    __builtin_amdgcn_global_load_lds(
        (const __attribute__((address_space(1))) unsigned int*)g,
        (__attribute__((address_space(3))) unsigned int*)l, 16, 0, 0);
}

// ------- k0_prep: xbT transpose (blk<2048) + weight prep (blk>=2048) -------
__global__ __launch_bounds__(256) void k0_prep(
    const float* __restrict__ x, const float* __restrict__ w_qkv,
    const float* __restrict__ w_out,
    unsigned short* __restrict__ xbT, unsigned short* __restrict__ wkvb,
    unsigned short* __restrict__ woutb, unsigned short* __restrict__ wqT)
{
    __shared__ float T[64][65];
    const int tid = threadIdx.x;
    const int blk0 = blockIdx.x;
    if (blk0 < 2048) {               // xbT[b][n][c] = bf16(x[b][c][n])
        const int n0 = (blk0 & 63) * 64, c0 = ((blk0 >> 6) & 3) * 64, b = blk0 >> 8;
        const float* xb = x + (size_t)b * 1048576;
        const int cr = tid >> 4, nc = (tid & 15) * 4;
        #pragma unroll
        for (int p = 0; p < 4; ++p) {
            float4 v = *(const float4*)(xb + (size_t)(c0 + cr + p * 16) * 4096 + n0 + nc);
            T[cr + p * 16][nc + 0] = v.x; T[cr + p * 16][nc + 1] = v.y;
            T[cr + p * 16][nc + 2] = v.z; T[cr + p * 16][nc + 3] = v.w;
        }
        __syncthreads();
        const int n = tid >> 2, cc = (tid & 3) * 16;
        unsigned short* dst = xbT + (size_t)b * 1048576 + (size_t)(n0 + n) * 256 + c0 + cc;
        #pragma unroll
        for (int g = 0; g < 4; ++g) {
            ushort4 o;
            o.x = f2bf(T[cc + g * 4 + 0][n]);
            o.y = f2bf(T[cc + g * 4 + 1][n]);
            o.z = f2bf(T[cc + g * 4 + 2][n]);
            o.w = f2bf(T[cc + g * 4 + 3][n]);
            *(ushort4*)(dst + g * 4) = o;
        }
        return;
    }
    const int blk = blk0 - 2048;
    if (blk < 256) {                 // wkvb: w_qkv rows 512..1536 -> bf16
        const int idx = (blk * 256 + tid) * 4;
        float4 v = *(const float4*)(w_qkv + 512 * 256 + idx);
        ushort4 o;
        o.x = f2bf(v.x); o.y = f2bf(v.y); o.z = f2bf(v.z); o.w = f2bf(v.w);
        *(ushort4*)(wkvb + idx) = o;
    } else if (blk < 384) {          // woutb: w_out -> bf16
        const int idx = ((blk - 256) * 256 + tid) * 4;
        float4 v = *(const float4*)(w_out + idx);
        ushort4 o;
        o.x = f2bf(v.x); o.y = f2bf(v.y); o.z = f2bf(v.z); o.w = f2bf(v.w);
        *(ushort4*)(woutb + idx) = o;
    } else {                         // wqT[c][j] = bf16(w_qkv[j][c]), j<512
        const int t = blk - 384;     // 32 tiles: 8 j-tiles x 4 c-tiles
        const int j0 = (t >> 2) * 64, c0 = (t & 3) * 64;
        const int r = tid >> 4, cc = (tid & 15) * 4;
        #pragma unroll
        for (int p = 0; p < 4; ++p) {
            float4 v = *(const float4*)(w_qkv + (j0 + r + p * 16) * 256 + c0 + cc);
            T[r + p * 16][cc + 0] = v.x; T[r + p * 16][cc + 1] = v.y;
            T[r + p * 16][cc + 2] = v.z; T[r + p * 16][cc + 3] = v.w;
        }
        __syncthreads();
        const int c = tid >> 2, jj = (tid & 3) * 16;
        #pragma unroll
        for (int g = 0; g < 4; ++g) {
            ushort4 o;
            o.x = f2bf(T[jj + g * 4 + 0][c]);
            o.y = f2bf(T[jj + g * 4 + 1][c]);
            o.z = f2bf(T[jj + g * 4 + 2][c]);
            o.w = f2bf(T[jj + g * 4 + 3][c]);
            *(ushort4*)(wqT + (c0 + c) * 512 + j0 + jj + g * 4) = o;
        }
    }
}

// ------------ k1r: kv[b][r][n] = sum_c wkvb[r][c]*xbT[b][n][c] -------------
// W rows rb*128 resident in LDS (64 KB, XOR involution layout, one barrier).
// X fragments loaded global->register directly. NO barriers in main loop.
// rb<4: K rows -> store exp(acc) + rowsum. rb>=4: V rows plain.
__global__ __launch_bounds__(256) void k1r(
    const unsigned short* __restrict__ wkvb,
    const unsigned short* __restrict__ xbT,
    unsigned short* __restrict__ kv, float* __restrict__ rowsum)
{
    __shared__ unsigned short Wl[32768];      // 8 k-subtiles x [128][32]
    const int tid  = threadIdx.x;
    const int w = tid >> 6, lane = tid & 63;
    const int quad = lane >> 4, l16 = lane & 15;
    const int wm = (w >> 1) * 64, wn = (w & 1) * 64;
    const int ns = blockIdx.x, rb = blockIdx.y, b = blockIdx.z;

    const unsigned short* Wg = wkvb + (size_t)(rb * 128) * 256;
    const unsigned short* Xb = xbT + (size_t)b * 1048576 + (size_t)ns * 131072;

    // W staging with source-side XOR involution (proven conflict-free, r6: 0 conflicts)
    const int c0 = w * 128 + lane, c1 = c0 + 64;
    const int r0 = c0 >> 2, s0 = ((c0 & 3) ^ ((r0 >> 1) & 3)) * 8;
    const int r1 = c1 >> 2, s1 = ((c1 & 3) ^ ((r1 >> 1) & 3)) * 8;
    const int ldsw = w * 1024;
    #pragma unroll
    for (int ks = 0; ks < 8; ++ks) {
        gl_lds16(Wg + (size_t)r0 * 256 + ks * 32 + s0, &Wl[ks * 4096 + ldsw]);
        gl_lds16(Wg + (size_t)r1 * 256 + ks * 32 + s1, &Wl[ks * 4096 + ldsw + 512]);
    }
    asm volatile("s_waitcnt vmcnt(0)" ::: "memory");
    __builtin_amdgcn_sched_barrier(0);
    __builtin_amdgcn_s_barrier();   // W resident; no further barriers needed

    float rsum[4][4] = {};
    unsigned short* Cb = kv + (size_t)b * 4194304 + (size_t)(rb * 128) * 4096
                       + (size_t)ns * 512;

    #pragma unroll 1
    for (int nsub = 0; nsub < 4; ++nsub) {
        // per-wave X row pointers for this 128-col subtile
        const unsigned short* px[4];
        #pragma unroll
        for (int nt = 0; nt < 4; ++nt)
            px[nt] = Xb + (size_t)(nsub * 128 + wn + nt * 16 + l16) * 256 + quad * 8;

        f32x4 acc[4][4] = {};
        #pragma unroll
        for (int ks = 0; ks < 8; ++ks) {
            frag8 a[4], bb[4];
            #pragma unroll
            for (int nt = 0; nt < 4; ++nt)
                bb[nt] = *(const frag8*)(px[nt] + ks * 32);
            #pragma unroll
            for (int mt = 0; mt < 4; ++mt) {
                const int ra = wm + mt * 16 + l16;
                a[mt] = *(const frag8*)(Wl + ks * 4096 + ra * 32
                                        + ((quad ^ ((ra >> 1) & 3)) << 3));
            }
            #pragma unroll
            for (int mt = 0; mt < 4; ++mt)
                #pragma unroll
                for (int nt = 0; nt < 4; ++nt)
                    acc[mt][nt] = __builtin_amdgcn_mfma_f32_16x16x32_bf16(
                        a[mt], bb[nt], acc[mt][nt], 0, 0, 0);
        }

        unsigned short* C = Cb + nsub * 128;
        if (rb < 4) {
            #pragma unroll
            for (int mt = 0; mt < 4; ++mt) {
                const int row = wm + mt * 16 + quad * 4;
                #pragma unroll
                for (int nt = 0; nt < 4; ++nt) {
                    const int col = wn + nt * 16 + l16;
                    #pragma unroll
                    for (int r = 0; r < 4; ++r) {
                        float e = __expf(acc[mt][nt][r]);
                        rsum[mt][r] += e;
                        C[(size_t)(row + r) * 4096 + col] = f2bf(e);
                    }
                }
            }
        } else {
            #pragma unroll
            for (int mt = 0; mt < 4; ++mt) {
                const int row = wm + mt * 16 + quad * 4;
                #pragma unroll
                for (int nt = 0; nt < 4; ++nt) {
                    const int col = wn + nt * 16 + l16;
                    #pragma unroll
                    for (int r = 0; r < 4; ++r)
                        C[(size_t)(row + r) * 4096 + col] = f2bf(acc[mt][nt][r]);
                }
            }
        }
    }

    if (rb < 4) {
        float* rs = rowsum + b * 512 + rb * 128;
        #pragma unroll
        for (int mt = 0; mt < 4; ++mt) {
            const int row = wm + mt * 16 + quad * 4;
            #pragma unroll
            for (int r = 0; r < 4; ++r) {
                float v = rsum[mt][r];
                v += __shfl_xor(v, 1, 64);
                v += __shfl_xor(v, 2, 64);
                v += __shfl_xor(v, 4, 64);
                v += __shfl_xor(v, 8, 64);
                if (l16 == 0) atomicAdd(rs + row + r, v);
            }
        }
    }
}

// ----- k3r: ctx[z][d][e] += sum_{n in slice} expK[z][d][n] * V[z][e][n] ----
// Both operands register-direct from kv; no LDS, no barriers.
// grid (16 slices of 256, 32 bh). atomicAdd f32 epilogue (write-through ~33MB).
__global__ __launch_bounds__(256) void k3r(
    const unsigned short* __restrict__ kv, float* __restrict__ ctx)
{
    const int tid  = threadIdx.x;
    const int w = tid >> 6, lane = tid & 63;
    const int quad = lane >> 4, l16 = lane & 15;
    const int wm = (w >> 1) * 64, wn = (w & 1) * 64;
    const int sl = blockIdx.x, z = blockIdx.y;

    const size_t off = (size_t)(z >> 2) * 4194304ull + (size_t)(z & 3) * 524288ull;
    const unsigned short* Ab = kv + off;                 // expK rows d
    const unsigned short* Bb = kv + off + 2097152ull;    // V rows e
    const int k0 = sl * 256;

    const unsigned short* pa[4];
    const unsigned short* pb[4];
    #pragma unroll
    for (int t = 0; t < 4; ++t) {
        pa[t] = Ab + (size_t)(wm + t * 16 + l16) * 4096 + k0 + quad * 8;
        pb[t] = Bb + (size_t)(wn + t * 16 + l16) * 4096 + k0 + quad * 8;
    }

    f32x4 acc[4][4] = {};
    #pragma unroll
    for (int ks = 0; ks < 8; ++ks) {
        frag8 a[4], bb[4];
        #pragma unroll
        for (int t = 0; t < 4; ++t) a[t]  = *(const frag8*)(pa[t] + ks * 32);
        #pragma unroll
        for (int t = 0; t < 4; ++t) bb[t] = *(const frag8*)(pb[t] + ks * 32);
        #pragma unroll
        for (int mt = 0; mt < 4; ++mt)
            #pragma unroll
            for (int nt = 0; nt < 4; ++nt)
                acc[mt][nt] = __builtin_amdgcn_mfma_f32_16x16x32_bf16(
                    a[mt], bb[nt], acc[mt][nt], 0, 0, 0);
    }

    float* C = ctx + (size_t)z * 16384ull;
    #pragma unroll
    for (int mt = 0; mt < 4; ++mt) {
        const int row = wm + mt * 16 + quad * 4;
        #pragma unroll
        for (int nt = 0; nt < 4; ++nt) {
            const int col = wn + nt * 16 + l16;
            #pragma unroll
            for (int r = 0; r < 4; ++r)
                atomicAdd(C + (row + r) * 128 + col, acc[mt][nt][r]);
        }
    }
}

// -------- MFMA gemm_bt: C[m][n] = sum_k A[m][k] * B[n][k]  (bf16 in) -------
// 128x128 tile, BK=32, 4 waves, dbuf 2-phase (round-10, passed).
// MODE 0: C bf16, z-strided (k5). MODE 1: C f32 + bias[row] (k6). MODE 3: k4.
template<int MODE>
__global__ __launch_bounds__(256) void mfma_bt(
    const unsigned short* __restrict__ A0, int lda,
    const unsigned short* __restrict__ B0, int ldb,
    void* __restrict__ C0, int ldc,
    const float* __restrict__ bias, int Kp,
    unsigned long long sAz, unsigned long long sBz, unsigned long long sCz)
{
    __shared__ unsigned short As[2][4096];
    __shared__ unsigned short Bs[2][4096];
    const int tid  = threadIdx.x;
    const int w    = tid >> 6, lane = tid & 63;
    const int quad = lane >> 4, l16 = lane & 15;
    const int wm = (w >> 1) * 64, wn = (w & 1) * 64;
    const int z = blockIdx.z;

    const unsigned short* A;
    const unsigned short* B;
    int m0, n0, NS;
    if constexpr (MODE == 3) {
        m0 = blockIdx.y * 128; n0 = 0;
        NS = Kp >> 5;
        A = A0 + (unsigned long long)(z & 3) * 128ull + (unsigned long long)m0 * lda;
        B = B0 + (unsigned long long)z * 16384ull;
    } else {
        m0 = blockIdx.y * 128; n0 = blockIdx.x * 128;
        NS = Kp >> 5;
        A = A0 + sAz * z + (unsigned long long)m0 * lda;
        B = B0 + sBz * z + (unsigned long long)n0 * ldb;
    }

    const int c0 = w * 128 + lane, c1 = c0 + 64;
    const int r0 = c0 >> 2, s0 = ((c0 & 3) ^ ((r0 >> 1) & 3)) * 8;
    const int r1 = c1 >> 2, s1 = ((c1 & 3) ^ ((r1 >> 1) & 3)) * 8;
    const unsigned short* gA0 = A + (unsigned long long)r0 * lda + s0;
    const unsigned short* gA1 = A + (unsigned long long)r1 * lda + s1;
    const unsigned short* gB0 = B + (unsigned long long)r0 * ldb + s0;
    const unsigned short* gB1 = B + (unsigned long long)r1 * ldb + s1;
    const int ldsw = w * 1024;

#define STG(T) do { \
        const int kk_ = (T) * 32; \
        gl_lds16(gA0 + kk_, &As[(T) & 1][ldsw]); \
        gl_lds16(gA1 + kk_, &As[(T) & 1][ldsw + 512]); \
        gl_lds16(gB0 + kk_, &Bs[(T) & 1][ldsw]); \
        gl_lds16(gB1 + kk_, &Bs[(T) & 1][ldsw + 512]); } while (0)

    STG(0); STG(1);
    asm volatile("s_waitcnt vmcnt(0)" ::: "memory");
    __builtin_amdgcn_sched_barrier(0);
    __builtin_amdgcn_s_barrier();
    __builtin_amdgcn_sched_barrier(0);

    f32x4 acc[4][4] = {};

    for (int t = 0; t < NS; ++t) {
        const unsigned short* as = As[t & 1];
        const unsigned short* bs = Bs[t & 1];
        frag8 a[4], bb[4];
        #pragma unroll
        for (int tt = 0; tt < 4; ++tt) {
            const int ra = wm + tt * 16 + l16;
            const int rn = wn + tt * 16 + l16;
            a[tt]  = *(const frag8*)(as + ra * 32 + ((quad ^ ((ra >> 1) & 3)) << 3));
            bb[tt] = *(const frag8*)(bs + rn * 32 + ((quad ^ ((rn >> 1) & 3)) << 3));
        }
        asm volatile("s_waitcnt lgkmcnt(0)" ::: "memory");
        __builtin_amdgcn_sched_barrier(0);
        __builtin_amdgcn_s_barrier();
        __builtin_amdgcn_sched_barrier(0);
        if (t + 2 < NS) STG(t + 2);
        #pragma unroll
        for (int mt = 0; mt < 4; ++mt)
            #pragma unroll
            for (int nt = 0; nt < 4; ++nt)
                acc[mt][nt] = __builtin_amdgcn_mfma_f32_16x16x32_bf16(
                    a[mt], bb[nt], acc[mt][nt], 0, 0, 0);
        if (t + 2 < NS) {
            asm volatile("s_waitcnt vmcnt(4)" ::: "memory");
        } else {
            asm volatile("s_waitcnt vmcnt(0)" ::: "memory");
        }
        __builtin_amdgcn_sched_barrier(0);
        __builtin_amdgcn_s_barrier();
        __builtin_amdgcn_sched_barrier(0);
    }
#undef STG

    // epilogue: C/D mapping col = lane&15, row = quad*4 + reg  [m91-verified]
    if constexpr (MODE == 0 || MODE == 3) {
        unsigned short* C;
        if constexpr (MODE == 0)
            C = (unsigned short*)C0 + sCz * z + (unsigned long long)m0 * ldc + n0;
        else
            C = (unsigned short*)C0 + (unsigned long long)(z >> 2) * 131072ull
              + (unsigned long long)(z & 3) * 128ull + (unsigned long long)m0 * ldc;
        #pragma unroll
        for (int mt = 0; mt < 4; ++mt) {
            const int row = wm + mt * 16 + quad * 4;
            #pragma unroll
            for (int nt = 0; nt < 4; ++nt) {
                const int col = wn + nt * 16 + l16;
                #pragma unroll
                for (int r = 0; r < 4; ++r)
                    C[(unsigned long long)(row + r) * ldc + col] = f2bf(acc[mt][nt][r]);
            }
        }
    } else {
        float* C = (float*)C0 + sCz * z + (unsigned long long)m0 * ldc + n0;
        const float* bp = bias + m0;
        #pragma unroll
        for (int mt = 0; mt < 4; ++mt) {
            const int row = wm + mt * 16 + quad * 4;
            #pragma unroll
            for (int nt = 0; nt < 4; ++nt) {
                const int col = wn + nt * 16 + l16;
                #pragma unroll
                for (int r = 0; r < 4; ++r)
                    C[(unsigned long long)(row + r) * ldc + col] = acc[mt][nt][r] + bp[row + r];
            }
        }
    }
}

// ---- k3_scale: ctxb[bh][d][e] = bf16( ctx[bh][d][e] / rowsum[bh*128+d] ) --
__global__ __launch_bounds__(256) void k3_scale(
    const float* __restrict__ ctx, const float* __restrict__ rowsum,
    unsigned short* __restrict__ ctxb)
{
    const int idx = (blockIdx.x * 256 + threadIdx.x) * 4;   // element index
    const float inv = 1.0f / rowsum[idx >> 7];              // row = bh*128+d
    float4 t = *(const float4*)(ctx + idx);
    ushort4 o;
    o.x = f2bf(t.x * inv); o.y = f2bf(t.y * inv);
    o.z = f2bf(t.z * inv); o.w = f2bf(t.w * inv);
    *(ushort4*)(ctxb + idx) = o;
}

extern "C" void kernel_launch(void* const* d_in, const int* in_sizes, int n_in,
                              void* d_out, int out_size, void* d_ws, size_t ws_size,
                              hipStream_t stream) {
    (void)in_sizes; (void)n_in; (void)out_size; (void)ws_size;
    const float* x     = (const float*)d_in[0];  // f32 [8,256,64,64]
    const float* w_qkv = (const float*)d_in[1];  // f32 [1536,256]
    const float* w_out = (const float*)d_in[2];  // f32 [256,512]
    const float* b_out = (const float*)d_in[3];  // f32 [256]
    float* out = (float*)d_out;                  // f32 [8,256,64,64]

    char* ws = (char*)d_ws;
    unsigned short* xbT    = (unsigned short*)ws;                 // 16,777,216
    unsigned short* wkvb   = (unsigned short*)(ws + 16777216);    //    524,288
    unsigned short* woutb  = (unsigned short*)(ws + 17301504);    //    262,144
    unsigned short* wqT    = (unsigned short*)(ws + 17563648);    //    262,144
    float*          ctx    = (float*)(ws + 17825792);             //  2,097,152
    float*          rowsum = (float*)(ws + 19922944);             //     16,384
    unsigned short* ctxb   = (unsigned short*)(ws + 19939328);    //  1,048,576
    unsigned short* Mb     = (unsigned short*)(ws + 20987904);    //  2,097,152
    unsigned short* Nb     = (unsigned short*)(ws + 23085056);    //  1,048,576
    unsigned short* kv     = (unsigned short*)(ws + 24133632);    // 67,108,864

    // zero atomic accumulators (ctx + rowsum, adjacent): 2,113,536 B
    hipMemsetAsync(ws + 17825792, 0, 2097152 + 16384, stream);

    k0_prep<<<dim3(2464), 256, 0, stream>>>(x, w_qkv, w_out, xbT, wkvb, woutb, wqT);
    // k1: kv (exp'd K rows + V rows), barrier-free W-resident
    k1r<<<dim3(8, 8, 8), 256, 0, stream>>>(wkvb, xbT, kv, rowsum);
    // k3: ctx atomically accumulated over 16 n-slices, barrier-free
    k3r<<<dim3(16, 32), 256, 0, stream>>>(kv, ctx);
    k3_scale<<<dim3(512), 256, 0, stream>>>(ctx, rowsum, ctxb);
    // k4: Mb[b][o][h*128+d] = sum_e woutb[o][h*128+e] * ctxb[bh][d][e]
    mfma_bt<3><<<dim3(1, 2, 32), 256, 0, stream>>>(
        woutb, 512, ctxb, 128, Mb, 512, nullptr, 128,
        0ull, 0ull, 0ull);
    // k5: Nb[b][o][c] = sum_j Mb[b][o][j] * wqT[c][j]
    mfma_bt<0><<<dim3(2, 2, 8), 256, 0, stream>>>(
        Mb, 512, wqT, 512, Nb, 256, nullptr, 512,
        131072ull, 0ull, 65536ull);
    // k6: out[b,o,n] = sum_c Nb[b,o,c] * xbT[b,n,c] + b_out[o]
    mfma_bt<1><<<dim3(32, 2, 8), 256, 0, stream>>>(
        Nb, 256, xbT, 256, out, 4096, b_out, 256,
        65536ull, 1048576ull, 1048576ull);
}

// Round 8
// 184.511 us; speedup vs baseline: 1.1615x; 1.1615x over previous
//
#include <hip/hip_runtime.h>
#include <stdint.h>

// LinearAttention on MI355X — round 12: best-measured assembly.
//  Evidence: k1 full-drain @2048 blocks = 49µs beats all pipelined variants
//  (61, 67µs); ctx atomics cost ~15µs vs split-8 ctxp plain stores (R0 vs R1).
//  So: R1's k1 (MODE4, exp+rowsum) + R0's k3 (MODE2 -> ctxp, plain stores)
//  + k3_sumscale (sum 8 slices, apply 1/rowsum). Staging XOR swizzle kept
//  everywhere (verified correct R3-R7; kills the 2.1M bank conflicts).
//
// final_b = N_b · x_b + bias;  N_b = (W_out ⊙ ctx_b) · W_q;
// ctx_b[h] = (1/rowsum) · exp(K)·V^T  (exp w/o max-subtraction: K~N(0,0.64), safe).
//
// ws layout (bytes):
//   xbT    bf16 [8][4096][256]     @ 0          (16,777,216)
//   wkvb   bf16 [1024][256]        @ 16777216   (   524,288)
//   woutb  bf16 [256][512]         @ 17301504   (   262,144)
//   wqT    bf16 [256][512]         @ 17563648   (   262,144)
//   ctxp   f32  [8][32][128][128]  @ 17825792   (16,777,216)  split-8 partials
//   rowsum f32  [8][512]           @ 34603008   (    16,384)  atomic accum
//   ctxb   bf16 [32][128][128]     @ 34619392   ( 1,048,576)
//   Mb     bf16 [8][256][512]      @ 35667968   ( 2,097,152)
//   Nb     bf16 [8][256][256]      @ 37765120   ( 1,048,576)
//   kv     bf16 [8][1024][4096]    @ 38813696   (67,108,864)  K part = exp(K)
// total 105,922,560 B

using frag8 = __attribute__((ext_vector_type(8))) short;   // 8 x bf16
using f32x4 = __attribute__((ext_vector_type(4))) float;

__device__ __forceinline__ unsigned short f2bf(float f) {
    union { float f; unsigned int u; } c; c.f = f;
    unsigned int u = c.u;
    return (unsigned short)((u + 0x7FFFu + ((u >> 16) & 1u)) >> 16);
}

__device__ __forceinline__ void gl_lds16(const void* g, void* l) {
    __builtin_amdgcn_global_load_lds(
        (const __attribute__((address_space(1))) unsigned int*)g,
        (__attribute__((address_space(3))) unsigned int*)l, 16, 0, 0);
}

// ------- k0_prep: xbT transpose (blk<2048) + weight prep (blk>=2048) -------
__global__ __launch_bounds__(256) void k0_prep(
    const float* __restrict__ x, const float* __restrict__ w_qkv,
    const float* __restrict__ w_out,
    unsigned short* __restrict__ xbT, unsigned short* __restrict__ wkvb,
    unsigned short* __restrict__ woutb, unsigned short* __restrict__ wqT)
{
    __shared__ float T[64][65];
    const int tid = threadIdx.x;
    const int blk0 = blockIdx.x;
    if (blk0 < 2048) {               // xbT[b][n][c] = bf16(x[b][c][n])
        const int n0 = (blk0 & 63) * 64, c0 = ((blk0 >> 6) & 3) * 64, b = blk0 >> 8;
        const float* xb = x + (size_t)b * 1048576;
        const int cr = tid >> 4, nc = (tid & 15) * 4;
        #pragma unroll
        for (int p = 0; p < 4; ++p) {
            float4 v = *(const float4*)(xb + (size_t)(c0 + cr + p * 16) * 4096 + n0 + nc);
            T[cr + p * 16][nc + 0] = v.x; T[cr + p * 16][nc + 1] = v.y;
            T[cr + p * 16][nc + 2] = v.z; T[cr + p * 16][nc + 3] = v.w;
        }
        __syncthreads();
        const int n = tid >> 2, cc = (tid & 3) * 16;
        unsigned short* dst = xbT + (size_t)b * 1048576 + (size_t)(n0 + n) * 256 + c0 + cc;
        #pragma unroll
        for (int g = 0; g < 4; ++g) {
            ushort4 o;
            o.x = f2bf(T[cc + g * 4 + 0][n]);
            o.y = f2bf(T[cc + g * 4 + 1][n]);
            o.z = f2bf(T[cc + g * 4 + 2][n]);
            o.w = f2bf(T[cc + g * 4 + 3][n]);
            *(ushort4*)(dst + g * 4) = o;
        }
        return;
    }
    const int blk = blk0 - 2048;
    if (blk < 256) {                 // wkvb: w_qkv rows 512..1536 -> bf16
        const int idx = (blk * 256 + tid) * 4;
        float4 v = *(const float4*)(w_qkv + 512 * 256 + idx);
        ushort4 o;
        o.x = f2bf(v.x); o.y = f2bf(v.y); o.z = f2bf(v.z); o.w = f2bf(v.w);
        *(ushort4*)(wkvb + idx) = o;
    } else if (blk < 384) {          // woutb: w_out -> bf16
        const int idx = ((blk - 256) * 256 + tid) * 4;
        float4 v = *(const float4*)(w_out + idx);
        ushort4 o;
        o.x = f2bf(v.x); o.y = f2bf(v.y); o.z = f2bf(v.z); o.w = f2bf(v.w);
        *(ushort4*)(woutb + idx) = o;
    } else {                         // wqT[c][j] = bf16(w_qkv[j][c]), j<512
        const int t = blk - 384;     // 32 tiles: 8 j-tiles x 4 c-tiles
        const int j0 = (t >> 2) * 64, c0 = (t & 3) * 64;
        const int r = tid >> 4, cc = (tid & 15) * 4;
        #pragma unroll
        for (int p = 0; p < 4; ++p) {
            float4 v = *(const float4*)(w_qkv + (j0 + r + p * 16) * 256 + c0 + cc);
            T[r + p * 16][cc + 0] = v.x; T[r + p * 16][cc + 1] = v.y;
            T[r + p * 16][cc + 2] = v.z; T[r + p * 16][cc + 3] = v.w;
        }
        __syncthreads();
        const int c = tid >> 2, jj = (tid & 3) * 16;
        #pragma unroll
        for (int g = 0; g < 4; ++g) {
            ushort4 o;
            o.x = f2bf(T[jj + g * 4 + 0][c]);
            o.y = f2bf(T[jj + g * 4 + 1][c]);
            o.z = f2bf(T[jj + g * 4 + 2][c]);
            o.w = f2bf(T[jj + g * 4 + 3][c]);
            *(ushort4*)(wqT + (c0 + c) * 512 + j0 + jj + g * 4) = o;
        }
    }
}

// -------- MFMA gemm_bt: C[m][n] = sum_k A[m][k] * B[n][k]  (bf16 in) -------
// 128x128 block tile, BK=32, 4 waves (each 64x64), 16x16x32 bf16 MFMA.
// Simple full-drain 2-phase loop (proven fastest @2048 blocks, R1: 49µs).
// Staging XOR involution swizzle: source k-slot ^= (row>>1)&3 (both sides).
// MODE 0: C bf16, z-strided (k5: N).
// MODE 1: C f32 + bias[row] (k6: out).
// MODE 2: k3 ctxp — single 128x128 tile per z=bh, k-slice = blockIdx.x*512,
//         plain f32 stores into ctxp[slice] (NO atomics).
// MODE 3: k4 M — A=woutb col-block h, B=ctxb[bh], C=Mb col-block h, bf16.
// MODE 4: k1 kv — like MODE 0, but blocks with blockIdx.y<4 (K rows) write
//         exp(acc) and atomicAdd per-row sums into rowsum (passed via bias).
template<int MODE>
__global__ __launch_bounds__(256) void mfma_bt(
    const unsigned short* __restrict__ A0, int lda,
    const unsigned short* __restrict__ B0, int ldb,
    void* __restrict__ C0, int ldc,
    const float* __restrict__ bias, int Kp,
    unsigned long long sAz, unsigned long long sBz, unsigned long long sCz)
{
    __shared__ unsigned short As[128 * 32];
    __shared__ unsigned short Bs[128 * 32];
    const int tid  = threadIdx.x;
    const int w    = tid >> 6, lane = tid & 63;
    const int quad = lane >> 4, l16 = lane & 15;
    const int wm = (w >> 1) * 64, wn = (w & 1) * 64;
    const int z = blockIdx.z;

    const unsigned short* A;
    const unsigned short* B;
    int m0, n0, ks, NS;
    if constexpr (MODE == 2) {
        m0 = 0; n0 = 0;
        ks = blockIdx.x * 512; NS = 16;
        const unsigned long long off =
            ((unsigned long long)(z >> 2) * 1024ull + (unsigned long long)(z & 3) * 128ull) * 4096ull;
        A = A0 + off; B = B0 + off;
    } else if constexpr (MODE == 3) {
        m0 = blockIdx.y * 128; n0 = 0;
        ks = 0; NS = Kp >> 5;   // 4
        A = A0 + (unsigned long long)(z & 3) * 128ull + (unsigned long long)m0 * lda;
        B = B0 + (unsigned long long)z * 16384ull;
    } else {
        m0 = blockIdx.y * 128; n0 = blockIdx.x * 128;
        ks = 0; NS = Kp >> 5;
        A = A0 + sAz * z + (unsigned long long)m0 * lda;
        B = B0 + sBz * z + (unsigned long long)n0 * ldb;
    }

    // staging: 512 chunks of 16B per tile; chunk c -> LDS row c>>2, slot c&3;
    // source slot pre-swizzled (involution, verified R3-R7)
    const int c0 = w * 128 + lane, c1 = c0 + 64;
    const int r0 = c0 >> 2, s0 = ((c0 & 3) ^ ((r0 >> 1) & 3)) * 8;
    const int r1 = c1 >> 2, s1 = ((c1 & 3) ^ ((r1 >> 1) & 3)) * 8;
    const unsigned short* gA0 = A + (unsigned long long)r0 * lda + s0 + ks;
    const unsigned short* gA1 = A + (unsigned long long)r1 * lda + s1 + ks;
    const unsigned short* gB0 = B + (unsigned long long)r0 * ldb + s0 + ks;
    const unsigned short* gB1 = B + (unsigned long long)r1 * ldb + s1 + ks;
    unsigned short* lA0 = As + w * 1024;
    unsigned short* lA1 = As + w * 1024 + 512;
    unsigned short* lB0 = Bs + w * 1024;
    unsigned short* lB1 = Bs + w * 1024 + 512;

    f32x4 acc[4][4] = {};

    for (int t = 0; t < NS; ++t) {
        const int k0 = t * 32;
        gl_lds16(gA0 + k0, lA0);
        gl_lds16(gA1 + k0, lA1);
        gl_lds16(gB0 + k0, lB0);
        gl_lds16(gB1 + k0, lB1);
        __syncthreads();
        frag8 a[4], b[4];
        #pragma unroll
        for (int tt = 0; tt < 4; ++tt) {
            const int ra = wm + tt * 16 + l16;
            const int rb = wn + tt * 16 + l16;
            a[tt] = *(const frag8*)(As + ra * 32 + ((quad ^ ((ra >> 1) & 3)) << 3));
            b[tt] = *(const frag8*)(Bs + rb * 32 + ((quad ^ ((rb >> 1) & 3)) << 3));
        }
        #pragma unroll
        for (int mt = 0; mt < 4; ++mt)
            #pragma unroll
            for (int nt = 0; nt < 4; ++nt)
                acc[mt][nt] = __builtin_amdgcn_mfma_f32_16x16x32_bf16(
                    a[mt], b[nt], acc[mt][nt], 0, 0, 0);
        __syncthreads();
    }

    // epilogue: C/D mapping col = lane&15, row = quad*4 + reg  [m91-verified]
    if constexpr (MODE == 0 || MODE == 3) {
        unsigned short* C;
        if constexpr (MODE == 0)
            C = (unsigned short*)C0 + sCz * z + (unsigned long long)m0 * ldc + n0;
        else
            C = (unsigned short*)C0 + (unsigned long long)(z >> 2) * 131072ull
              + (unsigned long long)(z & 3) * 128ull + (unsigned long long)m0 * ldc;
        #pragma unroll
        for (int mt = 0; mt < 4; ++mt) {
            const int row = wm + mt * 16 + quad * 4;
            #pragma unroll
            for (int nt = 0; nt < 4; ++nt) {
                const int col = wn + nt * 16 + l16;
                #pragma unroll
                for (int r = 0; r < 4; ++r)
                    C[(unsigned long long)(row + r) * ldc + col] = f2bf(acc[mt][nt][r]);
            }
        }
    } else if constexpr (MODE == 4) {
        unsigned short* C = (unsigned short*)C0 + sCz * z + (unsigned long long)m0 * ldc + n0;
        if (blockIdx.y < 4) {
            // K rows: write exp(acc), accumulate per-row sums -> atomic rowsum
            float* rs = (float*)bias;   // rowsum base, f32 [8][512]
            #pragma unroll
            for (int mt = 0; mt < 4; ++mt) {
                const int row = wm + mt * 16 + quad * 4;
                float rsum[4] = {0.f, 0.f, 0.f, 0.f};
                #pragma unroll
                for (int nt = 0; nt < 4; ++nt) {
                    const int col = wn + nt * 16 + l16;
                    #pragma unroll
                    for (int r = 0; r < 4; ++r) {
                        float e = __expf(acc[mt][nt][r]);
                        rsum[r] += e;
                        C[(unsigned long long)(row + r) * ldc + col] = f2bf(e);
                    }
                }
                #pragma unroll
                for (int r = 0; r < 4; ++r) {
                    float v = rsum[r];
                    v += __shfl_xor(v, 1, 64);
                    v += __shfl_xor(v, 2, 64);
                    v += __shfl_xor(v, 4, 64);
                    v += __shfl_xor(v, 8, 64);
                    if (l16 == 0)
                        atomicAdd(rs + (unsigned long long)z * 512 + m0 + row + r, v);
                }
            }
        } else {
            // V rows: plain bf16 write
            #pragma unroll
            for (int mt = 0; mt < 4; ++mt) {
                const int row = wm + mt * 16 + quad * 4;
                #pragma unroll
                for (int nt = 0; nt < 4; ++nt) {
                    const int col = wn + nt * 16 + l16;
                    #pragma unroll
                    for (int r = 0; r < 4; ++r)
                        C[(unsigned long long)(row + r) * ldc + col] = f2bf(acc[mt][nt][r]);
                }
            }
        }
    } else if constexpr (MODE == 1) {
        float* C = (float*)C0 + sCz * z + (unsigned long long)m0 * ldc + n0;
        const float* bp = bias + m0;
        #pragma unroll
        for (int mt = 0; mt < 4; ++mt) {
            const int row = wm + mt * 16 + quad * 4;
            #pragma unroll
            for (int nt = 0; nt < 4; ++nt) {
                const int col = wn + nt * 16 + l16;
                #pragma unroll
                for (int r = 0; r < 4; ++r)
                    C[(unsigned long long)(row + r) * ldc + col] = acc[mt][nt][r] + bp[row + r];
            }
        }
    } else {
        // MODE 2: plain f32 stores into ctxp[slice] — NO atomics
        float* C = (float*)C0 + ((unsigned long long)blockIdx.x * 32 + z) * 16384ull;
        #pragma unroll
        for (int mt = 0; mt < 4; ++mt) {
            const int row = wm + mt * 16 + quad * 4;
            #pragma unroll
            for (int nt = 0; nt < 4; ++nt) {
                const int col = wn + nt * 16 + l16;
                #pragma unroll
                for (int r = 0; r < 4; ++r)
                    C[(row + r) * 128 + col] = acc[mt][nt][r];
            }
        }
    }
}

// -- k3_sumscale: ctxb[bh][d][e] = bf16( (sum_s ctxp[s][bh][d][e]) / rowsum ) --
__global__ __launch_bounds__(256) void k3_sumscale(
    const float* __restrict__ ctxp, const float* __restrict__ rowsum,
    unsigned short* __restrict__ ctxb)
{
    const int idx = (blockIdx.x * 256 + threadIdx.x) * 4;   // element index
    float4 s = make_float4(0.f, 0.f, 0.f, 0.f);
    #pragma unroll
    for (int sl = 0; sl < 8; ++sl) {
        float4 t = *(const float4*)(ctxp + (size_t)sl * 524288 + idx);
        s.x += t.x; s.y += t.y; s.z += t.z; s.w += t.w;
    }
    const float inv = 1.0f / rowsum[idx >> 7];              // row = bh*128+d
    ushort4 o;
    o.x = f2bf(s.x * inv); o.y = f2bf(s.y * inv);
    o.z = f2bf(s.z * inv); o.w = f2bf(s.w * inv);
    *(ushort4*)(ctxb + idx) = o;
}

extern "C" void kernel_launch(void* const* d_in, const int* in_sizes, int n_in,
                              void* d_out, int out_size, void* d_ws, size_t ws_size,
                              hipStream_t stream) {
    (void)in_sizes; (void)n_in; (void)out_size; (void)ws_size;
    const float* x     = (const float*)d_in[0];  // f32 [8,256,64,64]
    const float* w_qkv = (const float*)d_in[1];  // f32 [1536,256]
    const float* w_out = (const float*)d_in[2];  // f32 [256,512]
    const float* b_out = (const float*)d_in[3];  // f32 [256]
    float* out = (float*)d_out;                  // f32 [8,256,64,64]

    char* ws = (char*)d_ws;
    unsigned short* xbT    = (unsigned short*)ws;                 // 16,777,216
    unsigned short* wkvb   = (unsigned short*)(ws + 16777216);    //    524,288
    unsigned short* woutb  = (unsigned short*)(ws + 17301504);    //    262,144
    unsigned short* wqT    = (unsigned short*)(ws + 17563648);    //    262,144
    float*          ctxp   = (float*)(ws + 17825792);             // 16,777,216
    float*          rowsum = (float*)(ws + 34603008);             //     16,384
    unsigned short* ctxb   = (unsigned short*)(ws + 34619392);    //  1,048,576
    unsigned short* Mb     = (unsigned short*)(ws + 35667968);    //  2,097,152
    unsigned short* Nb     = (unsigned short*)(ws + 37765120);    //  1,048,576
    unsigned short* kv     = (unsigned short*)(ws + 38813696);    // 67,108,864

    // zero rowsum only (16 KB — ctxp uses plain stores, no zeroing needed)
    hipMemsetAsync(ws + 34603008, 0, 16384, stream);

    k0_prep<<<dim3(2464), 256, 0, stream>>>(x, w_qkv, w_out, xbT, wkvb, woutb, wqT);
    // k1: kv[b,r,n] = sum_c wkvb[r,c]*xbT[b,n,c]; K rows stored as exp + rowsum
    mfma_bt<4><<<dim3(32, 8, 8), 256, 0, stream>>>(
        wkvb, 256, xbT, 256, kv, 4096, rowsum, 256,
        0ull, 1048576ull, 4194304ull);
    // k3: ctxp[s,bh,d,e] = sum_{n in slice s} expK[d,n]*V[e,n]  (plain stores)
    mfma_bt<2><<<dim3(8, 1, 32), 256, 0, stream>>>(
        kv, 4096, kv + (size_t)512 * 4096, 4096, ctxp, 128, nullptr, 0,
        0ull, 0ull, 0ull);
    // sum 8 slices + apply 1/rowsum -> ctxb bf16
    k3_sumscale<<<dim3(512), 256, 0, stream>>>(ctxp, rowsum, ctxb);
    // k4: Mb[b][o][h*128+d] = sum_e woutb[o][h*128+e] * ctxb[bh][d][e]
    mfma_bt<3><<<dim3(1, 2, 32), 256, 0, stream>>>(
        woutb, 512, ctxb, 128, Mb, 512, nullptr, 128,
        0ull, 0ull, 0ull);
    // k5: Nb[b][o][c] = sum_j Mb[b][o][j] * wqT[c][j]
    mfma_bt<0><<<dim3(2, 2, 8), 256, 0, stream>>>(
        Mb, 512, wqT, 512, Nb, 256, nullptr, 512,
        131072ull, 0ull, 65536ull);
    // k6: out[b,o,n] = sum_c Nb[b,o,c] * xbT[b,n,c] + b_out[o]
    mfma_bt<1><<<dim3(32, 2, 8), 256, 0, stream>>>(
        Nb, 256, xbT, 256, out, 4096, b_out, 256,
        65536ull, 1048576ull, 1048576ull);
}